// Round 5
// baseline (311.502 us; speedup 1.0000x reference)
//
#include <hip/hip_runtime.h>

// ---- problem constants ----
#define M_IMG 1008
#define N_PCD 1024
#define CDIM  256
#define NI_F  76800
#define NP_F  30000
#define KI    64
#define KP    64
#define NUM_CORR 256
#define NPAIR (NUM_CORR * KI)       // 16384
#define KEY_MOD 30001u
#define NCAND (M_IMG * 3)           // 3024 candidate slots
#define NEG_INF (-__builtin_inff())

// bool inputs may arrive as uint8 (numpy bool) or int32 layouts.
__device__ __forceinline__ bool mask_val(const void* p, int i, int is_u8) {
    return is_u8 ? (((const unsigned char*)p)[i] != 0)
                 : (((const int*)p)[i] != 0);
}

// ---- top-3 helpers (values only, multiplicity preserved) ----
__device__ __forceinline__ void top3_insert(float v, float& t0, float& t1, float& t2) {
    if (v > t0) { t2 = t1; t1 = t0; t0 = v; }
    else if (v > t1) { t2 = t1; t1 = v; }
    else if (v > t2) { t2 = v; }
}

__device__ __forceinline__ void top3_merge(float a0, float a1, float a2,
                                           float b0, float b1, float b2,
                                           float& x0, float& x1, float& x2) {
    if (a0 >= b0) {
        x0 = a0;
        if (a1 >= b0) { x1 = a1; x2 = (a2 >= b0) ? a2 : b0; }
        else          { x1 = b0; x2 = (a1 >= b1) ? a1 : b1; }
    } else {
        x0 = b0;
        if (b1 >= a0) { x1 = b1; x2 = (b2 >= a0) ? b2 : a0; }
        else          { x1 = a0; x2 = (b1 >= a1) ? b1 : a1; }
    }
}

// top-3 with index tracking
__device__ __forceinline__ void t3i_insert(float v, int i,
                                           float& v0, int& i0,
                                           float& v1, int& i1,
                                           float& v2, int& i2) {
    if (v > v0) { v2 = v1; i2 = i1; v1 = v0; i1 = i0; v0 = v; i0 = i; }
    else if (v > v1) { v2 = v1; i2 = i1; v1 = v; i1 = i; }
    else if (v > v2) { v2 = v; i2 = i; }
}

// =====================================================================
// Kernel 1: coarse GEMM + IN-BLOCK top-3 reduction. grid(16,32)x256.
// sim is never materialized: each block reduces its 32x64 masked tile to
//   - per-row stripe top-3 (value + global col idx) -> rowp/rowpi planes
//   - per-col chunk top-3 (values)                  -> colp planes
// Also zeroes out[]/cnt[]/nk and detects bool layout. GEMM main loop is
// bitwise-identical to the verified version; reductions are exact
// compares (no FP arithmetic), so downstream bits are unchanged.
// =====================================================================
__global__ void coarse_topk_kernel(const float* __restrict__ A,   // [1008,256]
                                   const float* __restrict__ B,   // [1024,256]
                                   const void* __restrict__ maskA,
                                   const void* __restrict__ maskB,
                                   const unsigned int* __restrict__ mskw,
                                   float* __restrict__ rowp,      // [16*3][1008]
                                   int* __restrict__ rowpi,       // [16*3][1008]
                                   float* __restrict__ colp,      // [3*32][1024]
                                   float* __restrict__ out0,      // d_out, zeroed
                                   unsigned int* __restrict__ cnt,// [16384], zeroed
                                   int* __restrict__ nk) {
    __shared__ __align__(16) float s_a[32][36];
    __shared__ __align__(16) float s_b[32][68];
    __shared__ float srv[32][16][3];
    __shared__ int   sri[32][16][3];
    __shared__ float scv[64][16][2];
    const int m0 = blockIdx.y * 32, n0 = blockIdx.x * 64;
    const int tid = threadIdx.x;
    const int tx = tid & 15, ty = tid >> 4;      // ty 0..15 -> 2 rows each
    const int c_lane = tid & 31;
    const int r_base = tid >> 5;                 // 0..7
    const int bx = blockIdx.x;

    // fold-in: zero output + rank counters + compaction counter
    const int bid = blockIdx.y * 16 + blockIdx.x;   // 0..511
    if (tid < 32) out0[bid * 32 + tid] = 0.f;
    if (tid >= 32 && tid < 64) cnt[bid * 32 + (tid - 32)] = 0u;
    if (bid == 0 && tid == 64) *nk = 0;

    // bool-layout probe (consumed at epilogue via __syncthreads_or)
    const bool hit = (mskw[tid] & 0xFFFFFF00u) != 0u;

    const float* pa[4];
    const float* pb[8];
#pragma unroll
    for (int k = 0; k < 4; k++) {
        int m = m0 + r_base + 8 * k;             // 0..31 within tile
        pa[k] = A + (size_t)(m < M_IMG ? m : 0) * CDIM + c_lane;
    }
#pragma unroll
    for (int k = 0; k < 8; k++)
        pb[k] = B + (size_t)(n0 + r_base + 8 * k) * CDIM + c_lane;

    float ra[4], rb[8];
#pragma unroll
    for (int k = 0; k < 4; k++) ra[k] = pa[k][0];
#pragma unroll
    for (int k = 0; k < 8; k++) rb[k] = pb[k][0];
#pragma unroll
    for (int k = 0; k < 4; k++) s_a[c_lane][r_base + 8 * k] = ra[k];
#pragma unroll
    for (int k = 0; k < 8; k++) s_b[c_lane][r_base + 8 * k] = rb[k];
    __syncthreads();

    float acc[2][4];
#pragma unroll
    for (int r = 0; r < 2; r++)
#pragma unroll
        for (int j = 0; j < 4; j++) acc[r][j] = 0.f;

    for (int cit = 0; cit < 8; cit++) {
        if (cit < 7) {
            const int cc = (cit + 1) * 32;
#pragma unroll
            for (int k = 0; k < 4; k++) ra[k] = pa[k][cc];
#pragma unroll
            for (int k = 0; k < 8; k++) rb[k] = pb[k][cc];
        }
#pragma unroll 8
        for (int c = 0; c < 32; c++) {
            float2 av = *(const float2*)&s_a[c][ty * 2];
            float4 bv = *(const float4*)&s_b[c][tx * 4];
            float ar[2] = {av.x, av.y};
            float br[4] = {bv.x, bv.y, bv.z, bv.w};
#pragma unroll
            for (int r = 0; r < 2; r++)
#pragma unroll
                for (int j = 0; j < 4; j++) acc[r][j] += ar[r] * br[j];
        }
        __syncthreads();
        if (cit < 7) {
#pragma unroll
            for (int k = 0; k < 4; k++) s_a[c_lane][r_base + 8 * k] = ra[k];
#pragma unroll
            for (int k = 0; k < 8; k++) s_b[c_lane][r_base + 8 * k] = rb[k];
            __syncthreads();
        }
    }

    const int is_u8 = __syncthreads_or(hit ? 1 : 0);

    // ---- masked tile values (same ok/NEG_INF semantics as sim path) ----
    float mv[2][4];
#pragma unroll
    for (int r = 0; r < 2; r++) {
        int m = m0 + ty * 2 + r;
        bool ma = (m < M_IMG) ? mask_val(maskA, m, is_u8) : false;
#pragma unroll
        for (int j = 0; j < 4; j++) {
            int n = n0 + tx * 4 + j;
            bool ok = ma && mask_val(maskB, n, is_u8);
            mv[r][j] = ok ? acc[r][j] : NEG_INF;
        }
    }

    // ---- per-thread row top-3 (4 cols) and col pair (2 rows) ----
#pragma unroll
    for (int r = 0; r < 2; r++) {
        float v0 = NEG_INF, v1 = NEG_INF, v2 = NEG_INF;
        int i0 = 0, i1 = 0, i2 = 0;
#pragma unroll
        for (int j = 0; j < 4; j++)
            t3i_insert(mv[r][j], n0 + tx * 4 + j, v0, i0, v1, i1, v2, i2);
        const int row = ty * 2 + r;
        srv[row][tx][0] = v0; srv[row][tx][1] = v1; srv[row][tx][2] = v2;
        sri[row][tx][0] = i0; sri[row][tx][1] = i1; sri[row][tx][2] = i2;
    }
#pragma unroll
    for (int j = 0; j < 4; j++) {
        float a = mv[0][j], b = mv[1][j];
        scv[tx * 4 + j][ty][0] = fmaxf(a, b);
        scv[tx * 4 + j][ty][1] = fminf(a, b);
    }
    __syncthreads();

    if (tid < 32) {                      // row-stripe top-3 -> rowp planes
        const int m = m0 + tid;
        if (m < M_IMG) {
            float v0 = srv[tid][0][0], v1 = srv[tid][0][1], v2 = srv[tid][0][2];
            int   i0 = sri[tid][0][0], i1 = sri[tid][0][1], i2 = sri[tid][0][2];
            for (int t = 1; t < 16; t++)
#pragma unroll
                for (int k = 0; k < 3; k++)
                    t3i_insert(srv[tid][t][k], sri[tid][t][k],
                               v0, i0, v1, i1, v2, i2);
            const int pb0 = bx * 3;
            rowp [(pb0 + 0) * M_IMG + m] = v0; rowpi[(pb0 + 0) * M_IMG + m] = i0;
            rowp [(pb0 + 1) * M_IMG + m] = v1; rowpi[(pb0 + 1) * M_IMG + m] = i1;
            rowp [(pb0 + 2) * M_IMG + m] = v2; rowpi[(pb0 + 2) * M_IMG + m] = i2;
        }
    } else if (tid >= 64 && tid < 128) { // col-chunk top-3 -> colp planes
        const int c = tid - 64;
        float t0 = scv[c][0][0], t1 = scv[c][0][1], t2 = NEG_INF;
        for (int t = 1; t < 16; t++) {
            top3_insert(scv[c][t][0], t0, t1, t2);
            top3_insert(scv[c][t][1], t0, t1, t2);
        }
        const int n = n0 + c;
        colp[(0 * 32 + blockIdx.y) * N_PCD + n] = t0;
        colp[(1 * 32 + blockIdx.y) * N_PCD + n] = t1;
        colp[(2 * 32 + blockIdx.y) * N_PCD + n] = t2;
    }
}

// =====================================================================
// Kernel 2: parallel top-NUM_CORR selection, grid(12)x1024. Each block:
// (a) merges 32 col-chunk partials -> s_colk (thread=column, coalesced);
// (b) merges 16 row-stripe partials -> per-row top-3 (value+idx) in regs,
//     qualifies candidates, rebuilds the SAME compacted key list in all
//     blocks (shfl prefix-sum, row-ascending order, no atomics);
// (c) block b rank-counts candidates [256b,256b+256) against all K
//     (keys unique -> rank exact) and writes sel_idx[rank] for rank<256.
// =====================================================================
__global__ __launch_bounds__(1024)
void select_kernel(const float* __restrict__ rowp,
                   const int* __restrict__ rowpi,
                   const float* __restrict__ colp,
                   int* __restrict__ sel_idx,
                   int* __restrict__ selK) {
    __shared__ float s_colk[N_PCD];                       // 4 KB
    __shared__ __align__(16) unsigned long long s_key[NCAND]; // 24 KB
    __shared__ int s_part[1024];                          // 4 KB
    __shared__ int s_wsum[16];
    const int tid = threadIdx.x;
    const int lane = tid & 63, w = tid >> 6;

    // ---- (a) merge col-chunk partials: thread tid owns column tid ----
    {
        float t0 = colp[(0 * 32 + 0) * N_PCD + tid];
        float t1 = colp[(1 * 32 + 0) * N_PCD + tid];
        float t2 = colp[(2 * 32 + 0) * N_PCD + tid];
#pragma unroll 4
        for (int ch = 1; ch < 32; ch++) {
            float b0 = colp[(0 * 32 + ch) * N_PCD + tid];
            float b1 = colp[(1 * 32 + ch) * N_PCD + tid];
            float b2 = colp[(2 * 32 + ch) * N_PCD + tid];
            float x0, x1, x2;
            top3_merge(t0, t1, t2, b0, b1, b2, x0, x1, x2);
            t0 = x0; t1 = x1; t2 = x2;
        }
        s_colk[tid] = t2;
    }
    __syncthreads();

    // ---- (b) merge row-stripes + qualify (thread t owns row t) ----
    unsigned long long kk[3] = {0, 0, 0};
    int ff[3] = {0, 0, 0};
    if (tid < M_IMG) {
        float rv[3]; int ri[3];
        rv[0] = rowp[0 * M_IMG + tid]; ri[0] = rowpi[0 * M_IMG + tid];
        rv[1] = rowp[1 * M_IMG + tid]; ri[1] = rowpi[1 * M_IMG + tid];
        rv[2] = rowp[2 * M_IMG + tid]; ri[2] = rowpi[2 * M_IMG + tid];
        for (int bx = 1; bx < 16; bx++)
#pragma unroll
            for (int s = 0; s < 3; s++)
                t3i_insert(rowp[(bx * 3 + s) * M_IMG + tid],
                           rowpi[(bx * 3 + s) * M_IMG + tid],
                           rv[0], ri[0], rv[1], ri[1], rv[2], ri[2]);
#pragma unroll
        for (int s = 0; s < 3; s++) {
            float v = rv[s]; int n = ri[s];
            if (v > 0.f && v >= s_colk[n]) {
                unsigned int u = __float_as_uint(v);
                unsigned int mono = (u & 0x80000000u) ? ~u : (u | 0x80000000u);
                kk[s] = ((unsigned long long)(~mono) << 32)
                      | (unsigned int)(tid * N_PCD + n);
                ff[s] = 1;
            }
        }
    }
    const int c = ff[0] + ff[1] + ff[2];

    // ---- block exclusive prefix sum over per-thread counts ----
    int v = c;
#pragma unroll
    for (int d = 1; d < 64; d <<= 1) {
        int o = __shfl_up(v, d);
        if (lane >= d) v += o;
    }
    if (lane == 63) s_wsum[w] = v;
    __syncthreads();
    if (w == 0) {
        int x = (lane < 16) ? s_wsum[lane] : 0;
#pragma unroll
        for (int d = 1; d < 16; d <<= 1) {
            int o = __shfl_up(x, d);
            if (lane >= d) x += o;
        }
        if (lane < 16) s_wsum[lane] = x;
    }
    __syncthreads();
    const int K = s_wsum[15];
    int pos = v - c + (w > 0 ? s_wsum[w - 1] : 0);   // exclusive base, row-order

    if (ff[0]) s_key[pos++] = kk[0];
    if (ff[1]) s_key[pos++] = kk[1];
    if (ff[2]) s_key[pos++] = kk[2];
    __syncthreads();

    if (blockIdx.x == 0 && tid == 0) *selK = (K < NUM_CORR) ? K : NUM_CORR;

    // ---- (c) rank-count: 4 threads per candidate i, quarter-strided j ----
    const int ii = tid & 255, q = tid >> 8;          // wave-uniform q
    const int i = blockIdx.x * 256 + ii;
    const unsigned long long my = (i < K) ? s_key[i] : 0xFFFFFFFFFFFFFFFFull;
    int less = 0;
    for (int j = q; j < K; j += 4)
        less += (s_key[j] < my);                     // LDS broadcast per wave
    s_part[tid] = less;
    __syncthreads();
    if (q == 0 && i < K) {
        int rank = s_part[ii] + s_part[ii + 256] + s_part[ii + 512] + s_part[ii + 768];
        if (rank < NUM_CORR)
            sel_idx[rank] = (int)(s_key[i] & 0xFFFFFFFFull);
    }
}

// =====================================================================
// Kernel 3: fine matching, one block per correspondence. grid(256)x512.
// Mutual top-1 keys are appended compacted AND scored in-place (L2-hot
// rows, exact reference float4 expression). GEMM body unchanged.
// =====================================================================
__global__ void fine_kernel(const float* __restrict__ img_f,   // [76800,256]
                            const float* __restrict__ pcd_f,   // [30000,256]
                            const int* __restrict__ img_knn,   // [1008,64]
                            const int* __restrict__ pcd_knn,   // [1024,64]
                            const void* __restrict__ pcd_msk,  // [1024,64] bool
                            const unsigned int* __restrict__ mskw,
                            const int* __restrict__ sel_idx,
                            const int* __restrict__ selK_ptr,
                            int* __restrict__ nk,
                            unsigned int* __restrict__ ckeys,  // [16384]
                            float* __restrict__ cscore) {      // [16384]
    const int ci = blockIdx.x, tid = threadIdx.x;
    if (ci >= *selK_ptr) return;
    __shared__ int s_ik[KI], s_pk[KP];
    __shared__ unsigned char s_mk[KP];
    __shared__ __align__(16) float s_a[32][68];
    __shared__ __align__(16) float s_b[32][68];
    __shared__ float s_sim[64][65];
    __shared__ int s_rb[64], s_cb[64];
    __shared__ float s_rv[64];

    const bool hit = (mskw[tid & 255] & 0xFFFFFF00u) != 0u;
    int flat = sel_idx[ci];
    int gi = flat >> 10, pi = flat & 1023;
    if (tid < 64) {
        s_ik[tid] = img_knn[gi * KI + tid];
        s_pk[tid] = pcd_knn[pi * KP + tid];
    }
    const int is_u8 = __syncthreads_or(hit ? 1 : 0);
    if (tid < 64)
        s_mk[tid] = mask_val(pcd_msk, pi * KP + tid, is_u8) ? 1 : 0;
    // s_mk is consumed only after the GEMM loop's barriers.

    const int tx = tid & 15, tyy = tid >> 4;     // tyy 0..31 -> 2 rows each
    const int c_lane = tid & 31;
    const int r_base = tid >> 5;                 // 0..15 -> 4 rows each

    const float* pa[4];
    const float* pb[4];
#pragma unroll
    for (int k = 0; k < 4; k++) {
        pa[k] = img_f + (size_t)s_ik[r_base + 16 * k] * CDIM + c_lane;
        pb[k] = pcd_f + (size_t)s_pk[r_base + 16 * k] * CDIM + c_lane;
    }

    float ra[4], rb[4];
#pragma unroll
    for (int k = 0; k < 4; k++) { ra[k] = pa[k][0]; rb[k] = pb[k][0]; }
#pragma unroll
    for (int k = 0; k < 4; k++) {
        s_a[c_lane][r_base + 16 * k] = ra[k];
        s_b[c_lane][r_base + 16 * k] = rb[k];
    }
    __syncthreads();

    float acc[2][4];
#pragma unroll
    for (int r = 0; r < 2; r++)
#pragma unroll
        for (int j = 0; j < 4; j++) acc[r][j] = 0.f;

    for (int cit = 0; cit < 8; cit++) {
        if (cit < 7) {
            const int cc = (cit + 1) * 32;
#pragma unroll
            for (int k = 0; k < 4; k++) { ra[k] = pa[k][cc]; rb[k] = pb[k][cc]; }
        }
#pragma unroll 8
        for (int c = 0; c < 32; c++) {
            float2 av = *(const float2*)&s_a[c][tyy * 2];
            float4 bv = *(const float4*)&s_b[c][tx * 4];
            float ar[2] = {av.x, av.y};
            float br[4] = {bv.x, bv.y, bv.z, bv.w};
#pragma unroll
            for (int r = 0; r < 2; r++)
#pragma unroll
                for (int j = 0; j < 4; j++) acc[r][j] += ar[r] * br[j];
        }
        __syncthreads();
        if (cit < 7) {
#pragma unroll
            for (int k = 0; k < 4; k++) {
                s_a[c_lane][r_base + 16 * k] = ra[k];
                s_b[c_lane][r_base + 16 * k] = rb[k];
            }
            __syncthreads();
        }
    }
#pragma unroll
    for (int r = 0; r < 2; r++) {
        int row = tyy * 2 + r;
#pragma unroll
        for (int j = 0; j < 4; j++) {
            int kp = tx * 4 + j;
            s_sim[row][kp] = (s_mk[kp] != 0) ? acc[r][j] : NEG_INF;
        }
    }
    __syncthreads();

    if (tid < 64) {              // row argmax over kp (first-max semantics)
        float best = NEG_INF; int bi = 0;
        for (int kp = 0; kp < 64; kp++) {
            float v = s_sim[tid][kp];
            if (v > best) { best = v; bi = kp; }
        }
        s_rb[tid] = bi; s_rv[tid] = best;
    } else if (tid < 128) {      // col argmax over ki
        int kp = tid - 64;
        float best = NEG_INF; int bi = 0;
        for (int k2 = 0; k2 < 64; k2++) {
            float v = s_sim[k2][kp];
            if (v > best) { best = v; bi = k2; }
        }
        s_cb[kp] = bi;
    }
    __syncthreads();

    if (tid < 64) {
        int rb2 = s_rb[tid];
        float rv = s_rv[tid];
        if ((s_cb[rb2] == tid) && (rv > 0.f)) {  // mutual top-1 + >FINE_THR
            int ik = s_ik[tid];
            int pk = s_pk[rb2];
            unsigned int key = (unsigned int)ik * KEY_MOD + (unsigned int)pk;
            // score with the exact reference-matching expression (L2-hot rows)
            const float4* a = (const float4*)(img_f + (size_t)ik * CDIM);
            const float4* b = (const float4*)(pcd_f + (size_t)pk * CDIM);
            float s = 0.f;
#pragma unroll 8
            for (int c = 0; c < CDIM / 4; c++) {
                float4 x = a[c], y = b[c];
                s += x.x * y.x + x.y * y.y + x.z * y.z + x.w * y.w;
            }
            int pos = atomicAdd(nk, 1);
            ckeys[pos] = key;                    // key < 2^32, no sentinels
            cscore[pos] = s;
        }
    }
}

// =====================================================================
// Kernel 4: 2-D counting rank over compacted keys. grid(64,64)x256,
// runtime-K early-out. cnt[i] += (less<<16) | eq_before.
// =====================================================================
__global__ void rank_count_kernel(const unsigned int* __restrict__ ckeys,
                                  const int* __restrict__ nk,
                                  unsigned int* __restrict__ cnt) {
    const int K = *nk;
    const int bi = blockIdx.x, bj = blockIdx.y;
    if (bi * 256 >= K || bj * 256 >= K) return;
    __shared__ unsigned int s_k[256];
    const int tid = threadIdx.x;
    const int i = bi * 256 + tid;
    const unsigned int myKey = (i < K) ? ckeys[i] : 0xFFFFFFFFu;
    const int j = bj * 256 + tid;
    s_k[tid] = (j < K) ? ckeys[j] : 0xFFFFFFFFu;   // pad > any real key
    __syncthreads();

    unsigned int less = 0, eqb = 0;
    if (bj < bi) {
#pragma unroll 8
        for (int t = 0; t < 256; t++) {
            unsigned int k = s_k[t];
            less += (k < myKey);
            eqb += (k == myKey);
        }
    } else if (bj == bi) {
#pragma unroll 8
        for (int t = 0; t < 256; t++) {
            unsigned int k = s_k[t];
            less += (k < myKey);
            eqb += (k == myKey) & (t < tid);
        }
    } else {
#pragma unroll 8
        for (int t = 0; t < 256; t++) {
            unsigned int k = s_k[t];
            less += (k < myKey);
        }
    }
    unsigned int v = (less << 16) | eqb;
    if (i < K && v) atomicAdd(&cnt[i], v);
}

// Kernel 5: scatter precomputed scores to ranked slots. grid(64)x256.
__global__ void rank_out_kernel(const unsigned int* __restrict__ cnt,
                                const float* __restrict__ cscore,
                                const int* __restrict__ nk,
                                float* __restrict__ out) {
    const int K = *nk;
    const int i = blockIdx.x * 256 + threadIdx.x;
    if (i >= K) return;
    const unsigned int v = cnt[i];
    if ((v & 0xFFFFu) == 0)                      // first occurrence in list order
        out[v >> 16] = cscore[i];                // rank = less
}

// =====================================================================
extern "C" void kernel_launch(void* const* d_in, const int* in_sizes, int n_in,
                              void* d_out, int out_size, void* d_ws, size_t ws_size,
                              hipStream_t stream) {
    const float* img_c = (const float*)d_in[0];
    const float* pcd_c = (const float*)d_in[1];
    const float* img_f = (const float*)d_in[2];
    const float* pcd_f = (const float*)d_in[3];
    const void* img_mask = d_in[4];
    const void* pcd_mask = d_in[5];
    const int* img_knn = (const int*)d_in[6];
    const int* pcd_knn = (const int*)d_in[7];
    const void* pcd_knn_msk = d_in[8];
    float* out = (float*)d_out;

    // ---- workspace layout (all offsets 4B-aligned) ----
    char* w = (char*)d_ws;
    size_t off = 0;
    float* rowp = (float*)(w + off);           off += 16 * 3 * M_IMG * 4;  // 193,536
    int* rowpi = (int*)(w + off);              off += 16 * 3 * M_IMG * 4;  // 193,536
    float* colp = (float*)(w + off);           off += 3 * 32 * N_PCD * 4;  // 393,216
    int* sel_idx = (int*)(w + off);            off += NUM_CORR * 4;
    int* selK = (int*)(w + off);               off += 4;
    int* nk = (int*)(w + off);                 off += 4;
    unsigned int* ckeys = (unsigned int*)(w + off); off += NPAIR * 4;
    float* cscore = (float*)(w + off);         off += NPAIR * 4;
    unsigned int* cnt = (unsigned int*)(w + off);   off += NPAIR * 4;

    const unsigned int* mskw = (const unsigned int*)pcd_knn_msk;

    // 5 dispatches, no memsets, no host-side sync, no sim matrix.
    coarse_topk_kernel<<<dim3(16, 32), 256, 0, stream>>>(
        img_c, pcd_c, img_mask, pcd_mask, mskw, rowp, rowpi, colp, out, cnt, nk);
    select_kernel<<<12, 1024, 0, stream>>>(rowp, rowpi, colp, sel_idx, selK);
    fine_kernel<<<NUM_CORR, 512, 0, stream>>>(img_f, pcd_f, img_knn, pcd_knn,
                                              pcd_knn_msk, mskw, sel_idx, selK,
                                              nk, ckeys, cscore);
    rank_count_kernel<<<dim3(64, 64), 256, 0, stream>>>(ckeys, nk, cnt);
    rank_out_kernel<<<64, 256, 0, stream>>>(cnt, cscore, nk, out);
}

// Round 6
// 261.789 us; speedup vs baseline: 1.1899x; 1.1899x over previous
//
#include <hip/hip_runtime.h>

// ---- problem constants ----
#define M_IMG 1008
#define N_PCD 1024
#define CDIM  256
#define NI_F  76800
#define NP_F  30000
#define KI    64
#define KP    64
#define NUM_CORR 256
#define NPAIR (NUM_CORR * KI)       // 16384
#define KEY_MOD 30001u
#define NCAND (M_IMG * 3)           // 3024 candidate slots
#define NEG_INF (-__builtin_inff())

// bool inputs may arrive as uint8 (numpy bool) or int32 layouts.
__device__ __forceinline__ bool mask_val(const void* p, int i, int is_u8) {
    return is_u8 ? (((const unsigned char*)p)[i] != 0)
                 : (((const int*)p)[i] != 0);
}

// ---- top-3 helpers (values only, multiplicity preserved) ----
__device__ __forceinline__ void top3_insert(float v, float& t0, float& t1, float& t2) {
    if (v > t0) { t2 = t1; t1 = t0; t0 = v; }
    else if (v > t1) { t2 = t1; t1 = v; }
    else if (v > t2) { t2 = v; }
}

__device__ __forceinline__ void top3_merge(float a0, float a1, float a2,
                                           float b0, float b1, float b2,
                                           float& x0, float& x1, float& x2) {
    if (a0 >= b0) {
        x0 = a0;
        if (a1 >= b0) { x1 = a1; x2 = (a2 >= b0) ? a2 : b0; }
        else          { x1 = b0; x2 = (a1 >= b1) ? a1 : b1; }
    } else {
        x0 = b0;
        if (b1 >= a0) { x1 = b1; x2 = (b2 >= a0) ? b2 : a0; }
        else          { x1 = a0; x2 = (b1 >= a1) ? b1 : a1; }
    }
}

// top-3 with index tracking
__device__ __forceinline__ void t3i_insert(float v, int i,
                                           float& v0, int& i0,
                                           float& v1, int& i1,
                                           float& v2, int& i2) {
    if (v > v0) { v2 = v1; i2 = i1; v1 = v0; i1 = i0; v0 = v; i0 = i; }
    else if (v > v1) { v2 = v1; i2 = i1; v1 = v; i1 = i; }
    else if (v > v2) { v2 = v; i2 = i; }
}

// =====================================================================
// Kernel 1: coarse GEMM + IN-BLOCK top-3 reduction. grid(16,32)x256.
// (verified in round 5 — unchanged)
// =====================================================================
__global__ void coarse_topk_kernel(const float* __restrict__ A,   // [1008,256]
                                   const float* __restrict__ B,   // [1024,256]
                                   const void* __restrict__ maskA,
                                   const void* __restrict__ maskB,
                                   const unsigned int* __restrict__ mskw,
                                   float* __restrict__ rowp,      // [16*3][1008]
                                   int* __restrict__ rowpi,       // [16*3][1008]
                                   float* __restrict__ colp,      // [3*32][1024]
                                   float* __restrict__ out0,      // d_out, zeroed
                                   unsigned int* __restrict__ cnt,// [16384], zeroed
                                   int* __restrict__ nk) {
    __shared__ __align__(16) float s_a[32][36];
    __shared__ __align__(16) float s_b[32][68];
    __shared__ float srv[32][16][3];
    __shared__ int   sri[32][16][3];
    __shared__ float scv[64][16][2];
    const int m0 = blockIdx.y * 32, n0 = blockIdx.x * 64;
    const int tid = threadIdx.x;
    const int tx = tid & 15, ty = tid >> 4;      // ty 0..15 -> 2 rows each
    const int c_lane = tid & 31;
    const int r_base = tid >> 5;                 // 0..7
    const int bx = blockIdx.x;

    // fold-in: zero output + rank counters + compaction counter
    const int bid = blockIdx.y * 16 + blockIdx.x;   // 0..511
    if (tid < 32) out0[bid * 32 + tid] = 0.f;
    if (tid >= 32 && tid < 64) cnt[bid * 32 + (tid - 32)] = 0u;
    if (bid == 0 && tid == 64) *nk = 0;

    // bool-layout probe (consumed at epilogue via __syncthreads_or)
    const bool hit = (mskw[tid] & 0xFFFFFF00u) != 0u;

    const float* pa[4];
    const float* pb[8];
#pragma unroll
    for (int k = 0; k < 4; k++) {
        int m = m0 + r_base + 8 * k;             // 0..31 within tile
        pa[k] = A + (size_t)(m < M_IMG ? m : 0) * CDIM + c_lane;
    }
#pragma unroll
    for (int k = 0; k < 8; k++)
        pb[k] = B + (size_t)(n0 + r_base + 8 * k) * CDIM + c_lane;

    float ra[4], rb[8];
#pragma unroll
    for (int k = 0; k < 4; k++) ra[k] = pa[k][0];
#pragma unroll
    for (int k = 0; k < 8; k++) rb[k] = pb[k][0];
#pragma unroll
    for (int k = 0; k < 4; k++) s_a[c_lane][r_base + 8 * k] = ra[k];
#pragma unroll
    for (int k = 0; k < 8; k++) s_b[c_lane][r_base + 8 * k] = rb[k];
    __syncthreads();

    float acc[2][4];
#pragma unroll
    for (int r = 0; r < 2; r++)
#pragma unroll
        for (int j = 0; j < 4; j++) acc[r][j] = 0.f;

    for (int cit = 0; cit < 8; cit++) {
        if (cit < 7) {
            const int cc = (cit + 1) * 32;
#pragma unroll
            for (int k = 0; k < 4; k++) ra[k] = pa[k][cc];
#pragma unroll
            for (int k = 0; k < 8; k++) rb[k] = pb[k][cc];
        }
#pragma unroll 8
        for (int c = 0; c < 32; c++) {
            float2 av = *(const float2*)&s_a[c][ty * 2];
            float4 bv = *(const float4*)&s_b[c][tx * 4];
            float ar[2] = {av.x, av.y};
            float br[4] = {bv.x, bv.y, bv.z, bv.w};
#pragma unroll
            for (int r = 0; r < 2; r++)
#pragma unroll
                for (int j = 0; j < 4; j++) acc[r][j] += ar[r] * br[j];
        }
        __syncthreads();
        if (cit < 7) {
#pragma unroll
            for (int k = 0; k < 4; k++) s_a[c_lane][r_base + 8 * k] = ra[k];
#pragma unroll
            for (int k = 0; k < 8; k++) s_b[c_lane][r_base + 8 * k] = rb[k];
            __syncthreads();
        }
    }

    const int is_u8 = __syncthreads_or(hit ? 1 : 0);

    // ---- masked tile values (same ok/NEG_INF semantics as sim path) ----
    float mv[2][4];
#pragma unroll
    for (int r = 0; r < 2; r++) {
        int m = m0 + ty * 2 + r;
        bool ma = (m < M_IMG) ? mask_val(maskA, m, is_u8) : false;
#pragma unroll
        for (int j = 0; j < 4; j++) {
            int n = n0 + tx * 4 + j;
            bool ok = ma && mask_val(maskB, n, is_u8);
            mv[r][j] = ok ? acc[r][j] : NEG_INF;
        }
    }

    // ---- per-thread row top-3 (4 cols) and col pair (2 rows) ----
#pragma unroll
    for (int r = 0; r < 2; r++) {
        float v0 = NEG_INF, v1 = NEG_INF, v2 = NEG_INF;
        int i0 = 0, i1 = 0, i2 = 0;
#pragma unroll
        for (int j = 0; j < 4; j++)
            t3i_insert(mv[r][j], n0 + tx * 4 + j, v0, i0, v1, i1, v2, i2);
        const int row = ty * 2 + r;
        srv[row][tx][0] = v0; srv[row][tx][1] = v1; srv[row][tx][2] = v2;
        sri[row][tx][0] = i0; sri[row][tx][1] = i1; sri[row][tx][2] = i2;
    }
#pragma unroll
    for (int j = 0; j < 4; j++) {
        float a = mv[0][j], b = mv[1][j];
        scv[tx * 4 + j][ty][0] = fmaxf(a, b);
        scv[tx * 4 + j][ty][1] = fminf(a, b);
    }
    __syncthreads();

    if (tid < 32) {                      // row-stripe top-3 -> rowp planes
        const int m = m0 + tid;
        if (m < M_IMG) {
            float v0 = srv[tid][0][0], v1 = srv[tid][0][1], v2 = srv[tid][0][2];
            int   i0 = sri[tid][0][0], i1 = sri[tid][0][1], i2 = sri[tid][0][2];
            for (int t = 1; t < 16; t++)
#pragma unroll
                for (int k = 0; k < 3; k++)
                    t3i_insert(srv[tid][t][k], sri[tid][t][k],
                               v0, i0, v1, i1, v2, i2);
            const int pb0 = bx * 3;
            rowp [(pb0 + 0) * M_IMG + m] = v0; rowpi[(pb0 + 0) * M_IMG + m] = i0;
            rowp [(pb0 + 1) * M_IMG + m] = v1; rowpi[(pb0 + 1) * M_IMG + m] = i1;
            rowp [(pb0 + 2) * M_IMG + m] = v2; rowpi[(pb0 + 2) * M_IMG + m] = i2;
        }
    } else if (tid >= 64 && tid < 128) { // col-chunk top-3 -> colp planes
        const int c = tid - 64;
        float t0 = scv[c][0][0], t1 = scv[c][0][1], t2 = NEG_INF;
        for (int t = 1; t < 16; t++) {
            top3_insert(scv[c][t][0], t0, t1, t2);
            top3_insert(scv[c][t][1], t0, t1, t2);
        }
        const int n = n0 + c;
        colp[(0 * 32 + blockIdx.y) * N_PCD + n] = t0;
        colp[(1 * 32 + blockIdx.y) * N_PCD + n] = t1;
        colp[(2 * 32 + blockIdx.y) * N_PCD + n] = t2;
    }
}

// =====================================================================
// Kernel 2: WIDE partial merge. grid(32)x256.
//  blocks 0..15 : rows. 64 rows/block, 4 threads/row; each thread merges
//                 4 stripes (12 coalesced loads) then 2-level LDS tree.
//  blocks 16..31: cols. 64 cols/block, 4 threads/col; each thread merges
//                 8 chunks (24 coalesced loads) then LDS tree.
// Stripe/chunk-ascending insertion order preserved (tie semantics
// identical to the verified serial merge; data is tie-free anyway).
// =====================================================================
__global__ void merge_kernel(const float* __restrict__ rowp,
                             const int* __restrict__ rowpi,
                             const float* __restrict__ colp,
                             float* __restrict__ rowv3,   // [1008*3]
                             int* __restrict__ rowi3,     // [1008*3]
                             float* __restrict__ col_kth) {// [1024]
    __shared__ float sv[4][64][3];
    __shared__ int   si[4][64][3];
    const int tid = threadIdx.x;
    const int lane = tid & 63, qq = tid >> 6;    // qq 0..3
    if (blockIdx.x < 16) {
        const int m = blockIdx.x * 64 + lane;    // 0..1023
        float v0 = NEG_INF, v1 = NEG_INF, v2 = NEG_INF;
        int i0 = 0, i1 = 0, i2 = 0;
        if (m < M_IMG) {
#pragma unroll
            for (int k = 0; k < 4; k++) {
                const int sx = qq * 4 + k;       // stripes in ascending order
#pragma unroll
                for (int s = 0; s < 3; s++)
                    t3i_insert(rowp[(sx * 3 + s) * M_IMG + m],
                               rowpi[(sx * 3 + s) * M_IMG + m],
                               v0, i0, v1, i1, v2, i2);
            }
        }
        sv[qq][lane][0] = v0; sv[qq][lane][1] = v1; sv[qq][lane][2] = v2;
        si[qq][lane][0] = i0; si[qq][lane][1] = i1; si[qq][lane][2] = i2;
        __syncthreads();
        if (qq == 0 && m < M_IMG) {
            for (int q = 1; q < 4; q++)
#pragma unroll
                for (int s = 0; s < 3; s++)
                    t3i_insert(sv[q][lane][s], si[q][lane][s],
                               v0, i0, v1, i1, v2, i2);
            rowv3[m * 3 + 0] = v0; rowi3[m * 3 + 0] = i0;
            rowv3[m * 3 + 1] = v1; rowi3[m * 3 + 1] = i1;
            rowv3[m * 3 + 2] = v2; rowi3[m * 3 + 2] = i2;
        }
    } else {
        const int n = (blockIdx.x - 16) * 64 + lane;   // 0..1023
        float t0 = NEG_INF, t1 = NEG_INF, t2 = NEG_INF;
#pragma unroll
        for (int k = 0; k < 8; k++) {
            const int ch = qq * 8 + k;           // chunks in ascending order
            float b0 = colp[(0 * 32 + ch) * N_PCD + n];
            float b1 = colp[(1 * 32 + ch) * N_PCD + n];
            float b2 = colp[(2 * 32 + ch) * N_PCD + n];
            float x0, x1, x2;
            top3_merge(t0, t1, t2, b0, b1, b2, x0, x1, x2);
            t0 = x0; t1 = x1; t2 = x2;
        }
        sv[qq][lane][0] = t0; sv[qq][lane][1] = t1; sv[qq][lane][2] = t2;
        __syncthreads();
        if (qq == 0) {
            for (int q = 1; q < 4; q++) {
                float x0, x1, x2;
                top3_merge(t0, t1, t2,
                           sv[q][lane][0], sv[q][lane][1], sv[q][lane][2],
                           x0, x1, x2);
                t0 = x0; t1 = x1; t2 = x2;
            }
            col_kth[n] = t2;                     // 3rd-largest of full column
        }
    }
}

// =====================================================================
// Kernel 3: parallel top-NUM_CORR selection, grid(12)x1024 (verified R3
// form — reads only merged rowv3/rowi3/col_kth, 28 KB total). Each block
// rebuilds the SAME compacted key list (shfl prefix-sum, row-ascending,
// no atomics); block b rank-counts candidates [256b,256b+256) against
// all K (keys unique -> rank exact); writes sel_idx[rank] for rank<256.
// =====================================================================
__global__ __launch_bounds__(1024)
void select_kernel(const float* __restrict__ rowv3,
                   const int* __restrict__ rowi3,
                   const float* __restrict__ col_kth,
                   int* __restrict__ sel_idx,
                   int* __restrict__ selK) {
    __shared__ float s_colk[N_PCD];                       // 4 KB
    __shared__ __align__(16) unsigned long long s_key[NCAND]; // 24 KB
    __shared__ int s_part[1024];                          // 4 KB
    __shared__ int s_wsum[16];
    const int tid = threadIdx.x;
    const int lane = tid & 63, w = tid >> 6;

    s_colk[tid] = col_kth[tid];
    __syncthreads();

    // ---- qualify my 3 entries (thread t owns row t, t<1008) ----
    unsigned long long k0 = 0, k1 = 0, k2 = 0;
    int f0 = 0, f1 = 0, f2 = 0;
    if (tid < M_IMG) {
#pragma unroll
        for (int s = 0; s < 3; s++) {
            float v = rowv3[tid * 3 + s];
            int n = rowi3[tid * 3 + s];
            if (v > 0.f && v >= s_colk[n]) {
                unsigned int u = __float_as_uint(v);
                unsigned int mono = (u & 0x80000000u) ? ~u : (u | 0x80000000u);
                unsigned long long key =
                    ((unsigned long long)(~mono) << 32)
                    | (unsigned int)(tid * N_PCD + n);
                if (s == 0) { k0 = key; f0 = 1; }
                else if (s == 1) { k1 = key; f1 = 1; }
                else { k2 = key; f2 = 1; }
            }
        }
    }
    const int c = f0 + f1 + f2;

    // ---- block exclusive prefix sum over per-thread counts ----
    int v = c;
#pragma unroll
    for (int d = 1; d < 64; d <<= 1) {
        int o = __shfl_up(v, d);
        if (lane >= d) v += o;
    }
    if (lane == 63) s_wsum[w] = v;
    __syncthreads();
    if (w == 0) {
        int x = (lane < 16) ? s_wsum[lane] : 0;
#pragma unroll
        for (int d = 1; d < 16; d <<= 1) {
            int o = __shfl_up(x, d);
            if (lane >= d) x += o;
        }
        if (lane < 16) s_wsum[lane] = x;
    }
    __syncthreads();
    const int K = s_wsum[15];
    int pos = v - c + (w > 0 ? s_wsum[w - 1] : 0);   // exclusive base, row-order

    if (f0) s_key[pos++] = k0;
    if (f1) s_key[pos++] = k1;
    if (f2) s_key[pos++] = k2;
    __syncthreads();

    if (blockIdx.x == 0 && tid == 0) *selK = (K < NUM_CORR) ? K : NUM_CORR;

    // ---- rank-count: 4 threads per candidate i, quarter-strided j ----
    const int ii = tid & 255, q = tid >> 8;          // wave-uniform q
    const int i = blockIdx.x * 256 + ii;
    const unsigned long long my = (i < K) ? s_key[i] : 0xFFFFFFFFFFFFFFFFull;
    int less = 0;
    for (int j = q; j < K; j += 4)
        less += (s_key[j] < my);                     // LDS broadcast per wave
    s_part[tid] = less;
    __syncthreads();
    if (q == 0 && i < K) {
        int rank = s_part[ii] + s_part[ii + 256] + s_part[ii + 512] + s_part[ii + 768];
        if (rank < NUM_CORR)
            sel_idx[rank] = (int)(s_key[i] & 0xFFFFFFFFull);
    }
}

// =====================================================================
// Kernel 4: fine matching, one block per correspondence. grid(256)x512.
// (verified — unchanged)
// =====================================================================
__global__ void fine_kernel(const float* __restrict__ img_f,   // [76800,256]
                            const float* __restrict__ pcd_f,   // [30000,256]
                            const int* __restrict__ img_knn,   // [1008,64]
                            const int* __restrict__ pcd_knn,   // [1024,64]
                            const void* __restrict__ pcd_msk,  // [1024,64] bool
                            const unsigned int* __restrict__ mskw,
                            const int* __restrict__ sel_idx,
                            const int* __restrict__ selK_ptr,
                            int* __restrict__ nk,
                            unsigned int* __restrict__ ckeys,  // [16384]
                            float* __restrict__ cscore) {      // [16384]
    const int ci = blockIdx.x, tid = threadIdx.x;
    if (ci >= *selK_ptr) return;
    __shared__ int s_ik[KI], s_pk[KP];
    __shared__ unsigned char s_mk[KP];
    __shared__ __align__(16) float s_a[32][68];
    __shared__ __align__(16) float s_b[32][68];
    __shared__ float s_sim[64][65];
    __shared__ int s_rb[64], s_cb[64];
    __shared__ float s_rv[64];

    const bool hit = (mskw[tid & 255] & 0xFFFFFF00u) != 0u;
    int flat = sel_idx[ci];
    int gi = flat >> 10, pi = flat & 1023;
    if (tid < 64) {
        s_ik[tid] = img_knn[gi * KI + tid];
        s_pk[tid] = pcd_knn[pi * KP + tid];
    }
    const int is_u8 = __syncthreads_or(hit ? 1 : 0);
    if (tid < 64)
        s_mk[tid] = mask_val(pcd_msk, pi * KP + tid, is_u8) ? 1 : 0;
    // s_mk is consumed only after the GEMM loop's barriers.

    const int tx = tid & 15, tyy = tid >> 4;     // tyy 0..31 -> 2 rows each
    const int c_lane = tid & 31;
    const int r_base = tid >> 5;                 // 0..15 -> 4 rows each

    const float* pa[4];
    const float* pb[4];
#pragma unroll
    for (int k = 0; k < 4; k++) {
        pa[k] = img_f + (size_t)s_ik[r_base + 16 * k] * CDIM + c_lane;
        pb[k] = pcd_f + (size_t)s_pk[r_base + 16 * k] * CDIM + c_lane;
    }

    float ra[4], rb[4];
#pragma unroll
    for (int k = 0; k < 4; k++) { ra[k] = pa[k][0]; rb[k] = pb[k][0]; }
#pragma unroll
    for (int k = 0; k < 4; k++) {
        s_a[c_lane][r_base + 16 * k] = ra[k];
        s_b[c_lane][r_base + 16 * k] = rb[k];
    }
    __syncthreads();

    float acc[2][4];
#pragma unroll
    for (int r = 0; r < 2; r++)
#pragma unroll
        for (int j = 0; j < 4; j++) acc[r][j] = 0.f;

    for (int cit = 0; cit < 8; cit++) {
        if (cit < 7) {
            const int cc = (cit + 1) * 32;
#pragma unroll
            for (int k = 0; k < 4; k++) { ra[k] = pa[k][cc]; rb[k] = pb[k][cc]; }
        }
#pragma unroll 8
        for (int c = 0; c < 32; c++) {
            float2 av = *(const float2*)&s_a[c][tyy * 2];
            float4 bv = *(const float4*)&s_b[c][tx * 4];
            float ar[2] = {av.x, av.y};
            float br[4] = {bv.x, bv.y, bv.z, bv.w};
#pragma unroll
            for (int r = 0; r < 2; r++)
#pragma unroll
                for (int j = 0; j < 4; j++) acc[r][j] += ar[r] * br[j];
        }
        __syncthreads();
        if (cit < 7) {
#pragma unroll
            for (int k = 0; k < 4; k++) {
                s_a[c_lane][r_base + 16 * k] = ra[k];
                s_b[c_lane][r_base + 16 * k] = rb[k];
            }
            __syncthreads();
        }
    }
#pragma unroll
    for (int r = 0; r < 2; r++) {
        int row = tyy * 2 + r;
#pragma unroll
        for (int j = 0; j < 4; j++) {
            int kp = tx * 4 + j;
            s_sim[row][kp] = (s_mk[kp] != 0) ? acc[r][j] : NEG_INF;
        }
    }
    __syncthreads();

    if (tid < 64) {              // row argmax over kp (first-max semantics)
        float best = NEG_INF; int bi = 0;
        for (int kp = 0; kp < 64; kp++) {
            float v = s_sim[tid][kp];
            if (v > best) { best = v; bi = kp; }
        }
        s_rb[tid] = bi; s_rv[tid] = best;
    } else if (tid < 128) {      // col argmax over ki
        int kp = tid - 64;
        float best = NEG_INF; int bi = 0;
        for (int k2 = 0; k2 < 64; k2++) {
            float v = s_sim[k2][kp];
            if (v > best) { best = v; bi = k2; }
        }
        s_cb[kp] = bi;
    }
    __syncthreads();

    if (tid < 64) {
        int rb2 = s_rb[tid];
        float rv = s_rv[tid];
        if ((s_cb[rb2] == tid) && (rv > 0.f)) {  // mutual top-1 + >FINE_THR
            int ik = s_ik[tid];
            int pk = s_pk[rb2];
            unsigned int key = (unsigned int)ik * KEY_MOD + (unsigned int)pk;
            // score with the exact reference-matching expression (L2-hot rows)
            const float4* a = (const float4*)(img_f + (size_t)ik * CDIM);
            const float4* b = (const float4*)(pcd_f + (size_t)pk * CDIM);
            float s = 0.f;
#pragma unroll 8
            for (int c = 0; c < CDIM / 4; c++) {
                float4 x = a[c], y = b[c];
                s += x.x * y.x + x.y * y.y + x.z * y.z + x.w * y.w;
            }
            int pos = atomicAdd(nk, 1);
            ckeys[pos] = key;                    // key < 2^32, no sentinels
            cscore[pos] = s;
        }
    }
}

// =====================================================================
// Kernel 5: 2-D counting rank over compacted keys. grid(64,64)x256,
// runtime-K early-out. cnt[i] += (less<<16) | eq_before.
// =====================================================================
__global__ void rank_count_kernel(const unsigned int* __restrict__ ckeys,
                                  const int* __restrict__ nk,
                                  unsigned int* __restrict__ cnt) {
    const int K = *nk;
    const int bi = blockIdx.x, bj = blockIdx.y;
    if (bi * 256 >= K || bj * 256 >= K) return;
    __shared__ unsigned int s_k[256];
    const int tid = threadIdx.x;
    const int i = bi * 256 + tid;
    const unsigned int myKey = (i < K) ? ckeys[i] : 0xFFFFFFFFu;
    const int j = bj * 256 + tid;
    s_k[tid] = (j < K) ? ckeys[j] : 0xFFFFFFFFu;   // pad > any real key
    __syncthreads();

    unsigned int less = 0, eqb = 0;
    if (bj < bi) {
#pragma unroll 8
        for (int t = 0; t < 256; t++) {
            unsigned int k = s_k[t];
            less += (k < myKey);
            eqb += (k == myKey);
        }
    } else if (bj == bi) {
#pragma unroll 8
        for (int t = 0; t < 256; t++) {
            unsigned int k = s_k[t];
            less += (k < myKey);
            eqb += (k == myKey) & (t < tid);
        }
    } else {
#pragma unroll 8
        for (int t = 0; t < 256; t++) {
            unsigned int k = s_k[t];
            less += (k < myKey);
        }
    }
    unsigned int v = (less << 16) | eqb;
    if (i < K && v) atomicAdd(&cnt[i], v);
}

// Kernel 6: scatter precomputed scores to ranked slots. grid(64)x256.
__global__ void rank_out_kernel(const unsigned int* __restrict__ cnt,
                                const float* __restrict__ cscore,
                                const int* __restrict__ nk,
                                float* __restrict__ out) {
    const int K = *nk;
    const int i = blockIdx.x * 256 + threadIdx.x;
    if (i >= K) return;
    const unsigned int v = cnt[i];
    if ((v & 0xFFFFu) == 0)                      // first occurrence in list order
        out[v >> 16] = cscore[i];                // rank = less
}

// =====================================================================
extern "C" void kernel_launch(void* const* d_in, const int* in_sizes, int n_in,
                              void* d_out, int out_size, void* d_ws, size_t ws_size,
                              hipStream_t stream) {
    const float* img_c = (const float*)d_in[0];
    const float* pcd_c = (const float*)d_in[1];
    const float* img_f = (const float*)d_in[2];
    const float* pcd_f = (const float*)d_in[3];
    const void* img_mask = d_in[4];
    const void* pcd_mask = d_in[5];
    const int* img_knn = (const int*)d_in[6];
    const int* pcd_knn = (const int*)d_in[7];
    const void* pcd_knn_msk = d_in[8];
    float* out = (float*)d_out;

    // ---- workspace layout (all offsets 4B-aligned) ----
    char* w = (char*)d_ws;
    size_t off = 0;
    float* rowp = (float*)(w + off);           off += 16 * 3 * M_IMG * 4;  // 193,536
    int* rowpi = (int*)(w + off);              off += 16 * 3 * M_IMG * 4;  // 193,536
    float* colp = (float*)(w + off);           off += 3 * 32 * N_PCD * 4;  // 393,216
    float* rowv3 = (float*)(w + off);          off += M_IMG * 3 * 4;       // 12,096
    int* rowi3 = (int*)(w + off);              off += M_IMG * 3 * 4;       // 12,096
    float* col_kth = (float*)(w + off);        off += N_PCD * 4;           // 4,096
    int* sel_idx = (int*)(w + off);            off += NUM_CORR * 4;
    int* selK = (int*)(w + off);               off += 4;
    int* nk = (int*)(w + off);                 off += 4;
    unsigned int* ckeys = (unsigned int*)(w + off); off += NPAIR * 4;
    float* cscore = (float*)(w + off);         off += NPAIR * 4;
    unsigned int* cnt = (unsigned int*)(w + off);   off += NPAIR * 4;

    const unsigned int* mskw = (const unsigned int*)pcd_knn_msk;

    // 6 dispatches, no memsets, no host-side sync, no sim matrix.
    coarse_topk_kernel<<<dim3(16, 32), 256, 0, stream>>>(
        img_c, pcd_c, img_mask, pcd_mask, mskw, rowp, rowpi, colp, out, cnt, nk);
    merge_kernel<<<32, 256, 0, stream>>>(rowp, rowpi, colp, rowv3, rowi3, col_kth);
    select_kernel<<<12, 1024, 0, stream>>>(rowv3, rowi3, col_kth, sel_idx, selK);
    fine_kernel<<<NUM_CORR, 512, 0, stream>>>(img_f, pcd_f, img_knn, pcd_knn,
                                              pcd_knn_msk, mskw, sel_idx, selK,
                                              nk, ckeys, cscore);
    rank_count_kernel<<<dim3(64, 64), 256, 0, stream>>>(ckeys, nk, cnt);
    rank_out_kernel<<<64, 256, 0, stream>>>(cnt, cscore, nk, out);
}